// Round 1
// baseline (68.798 us; speedup 1.0000x reference)
//
#include <hip/hip_runtime.h>

// HWnet_plus: windowed softmax-weighted embedding lookup.
// T=16384 bins over [0,1], D=128, window W=9 (EDGE=4), TAKECARE=10, B=8192.
//
// R7 = R6 restructured for latency hiding:
//  - 64 lanes per batch element (was 32), each lane owns 2 floats of D.
//    Wave count doubles: 8192 waves = 8 waves/SIMD (was 4) -> 2x the
//    in-flight gathers per SIMD. Traffic unchanged: the two softmax rows
//    are ADJACENT (step=+-1), so each lane loads vf2 from row rlo and
//    rlo+1 -> two fully coalesced 512B load instructions per wave.
//  - b = gid>>6 is wave-uniform -> inputs[b] is a scalar-load candidate,
//    off the vector-memory dependency chain.
//  - 1/(w1+wn) -> __builtin_amdgcn_rcpf (approx rcp; tolerance 9.4e-2,
//    rcp rel err ~1e-6 -> free).
//
// Approximation (verified in prior session): softmax peak row jc plus its
// NEARER neighbor; the farther neighbor is at distance >= 1.0 -> relative
// weight <= exp(-10) ~ 4.5e-5 -> <= ~4e-4 output error vs 9.375e-2 check
// threshold.
//
// Index math (exact, no table reads): bins are linspace with step 2^-14
// (power of two, exact in fp32):
//   min[k]=k*2^-14, max[k]=(k+1)*2^-14, center[k]=(k+0.5)*2^-14, /wide==*2^14
// idx = floor(x*2^14); if x*2^14 is integral (shared edge) the reference
// argmax picks the LOWER bin -> idx-1.

#define HW_T 16384
#define HW_D 128
#define HW_EDGE 4
#define HW_TAKECARE 10.0f
#define HW_INV_WIDE 16384.0f
#define HW_WIDE (1.0f / 16384.0f)

typedef float vf2 __attribute__((ext_vector_type(2)));

__global__ __launch_bounds__(256) void hwnet_kernel(
    const float* __restrict__ inputs,        // [B,1]
    const float* __restrict__ vec_table,     // [T,D]
    float* __restrict__ out,                 // [B,D]
    int B) {
    int gid = blockIdx.x * blockDim.x + threadIdx.x;
    int b = gid >> 6;          // 64 threads per batch element (wave-uniform)
    int c = (gid & 63) << 1;   // 2 floats of D per thread
    if (b >= B) return;

    float x = inputs[b];       // wave-uniform -> scalar load

    // Exact bin index.
    float u = x * HW_INV_WIDE;
    int k = (int)u;
    if (k > HW_T - 1) k = HW_T - 1;
    if (k < 0) k = 0;
    if ((float)k == u && k > 0) k -= 1;   // shared-edge: argmax picks lower bin
    int idx = k;

    int idx_clip = idx < HW_EDGE ? HW_EDGE
                 : (idx > HW_T - 1 - HW_EDGE ? HW_T - 1 - HW_EDGE : idx);

    float et   = ((float)(2 * idx + 1)) * (0.5f * HW_WIDE);   // exact center
    float dist = (x - et) * HW_INV_WIDE;                       // exact /wide
    float base = dist - (float)(idx_clip - idx);

    // Peak window offset (clamped so both chosen rows stay in [0,8]).
    int jc = (int)rintf(base) + HW_EDGE;
    jc = jc < 1 ? 1 : (jc > 7 ? 7 : jc);

    float d1 = base - (float)(jc - HW_EDGE);   // |d1| <= 0.5 (+clamp slack)
    // Nearer neighbor: jc+1 if d1 >= 0 else jc-1.
    int step = d1 >= 0.0f ? 1 : -1;
    float dn = d1 - (float)step;               // |dn| in [0.5, 1.0]
    float w1 = __expf(-HW_TAKECARE * d1 * d1);
    float wn = __expf(-HW_TAKECARE * dn * dn);
    float inv = __builtin_amdgcn_rcpf(w1 + wn);
    w1 *= inv; wn *= inv;

    // The two rows are adjacent: load both at vf2 width per lane.
    int row  = idx_clip - HW_EDGE + jc;        // peak row
    int rlo  = step > 0 ? row : row - 1;       // lower of the adjacent pair
    float w_lo = step > 0 ? w1 : wn;
    float w_hi = step > 0 ? wn : w1;

    const float* vt = vec_table + (size_t)rlo * HW_D + c;
    vf2 vlo = *(const vf2*)(vt);
    vf2 vhi = *(const vf2*)(vt + HW_D);

    vf2 acc = w_lo * vlo + w_hi * vhi;

    __builtin_nontemporal_store(acc, (vf2*)(out + (size_t)b * HW_D + c));
}

extern "C" void kernel_launch(void* const* d_in, const int* in_sizes, int n_in,
                              void* d_out, int out_size, void* d_ws, size_t ws_size,
                              hipStream_t stream) {
    const float* inputs    = (const float*)d_in[0];
    const float* vec_table = (const float*)d_in[4];
    float* out = (float*)d_out;

    int B = in_sizes[0];                 // 8192
    int total_threads = B * 64;          // 64 lanes per batch element
    dim3 block(256);
    dim3 grid((total_threads + block.x - 1) / block.x);
    hwnet_kernel<<<grid, block, 0, stream>>>(inputs, vec_table, out, B);
}